// Round 9
// baseline (564.283 us; speedup 1.0000x reference)
//
#include <hip/hip_runtime.h>
#include <hip/hip_bf16.h>

// ---------------------------------------------------------------------------
// mv3Dunet_down_text_cmsa forward. Round 9: conv restructured to ic-chunk
// blocks (30 KB LDS, 640-block grid, acc[2][4]) for occupancy; chunk-major
// bf16 XT layout [b][g][208][72]. Tail identical to round 8.
// ---------------------------------------------------------------------------

using bf16x8 = __attribute__((ext_vector_type(8))) short;
using f32x4  = __attribute__((ext_vector_type(4))) float;

__device__ __forceinline__ unsigned short f2bf(float f) {
    unsigned int u = __float_as_uint(f);
    u += 0x7FFFu + ((u >> 16) & 1u);
    return (unsigned short)(u >> 16);
}

// in-place softmax over s[0..len) using one wave's 64 lanes
__device__ __forceinline__ void softseg(float* s, int len, int lane) {
    float m = -3.4e38f;
    for (int j = lane; j < len; j += 64) m = fmaxf(m, s[j]);
    for (int sh = 32; sh; sh >>= 1) m = fmaxf(m, __shfl_xor(m, sh));
    float sum = 0.f;
    for (int j = lane; j < len; j += 64) { float e = expf(s[j] - m); s[j] = e; sum += e; }
    for (int sh = 32; sh; sh >>= 1) sum += __shfl_xor(sum, sh);
    float inv = 1.f / sum;
    for (int j = lane; j < len; j += 64) s[j] *= inv;
}

// ---------------- X -> chunk-major bf16: xt[b][g][208][72] ----------------
__global__ void k_xt_c(const float* __restrict__ x, unsigned short* __restrict__ xt,
                       int IC, int G) {
    int b = blockIdx.y;
    int tot = G * 208 * 36;                  // uint writes
    int idx = blockIdx.x * 256 + threadIdx.x;
    if (idx >= tot) return;
    int g = idx / (208 * 36); int r = idx - g * 208 * 36;
    int s = r / 36, cp = r - s * 36;
    int cc = cp * 2;
    int ic = g * 64 + cc;
    unsigned int lo = 0, hi = 0;
    if (s < 196 && cc < 64 && ic < IC)         lo = f2bf(x[((size_t)b * IC + ic) * 196 + s]);
    if (s < 196 && cc + 1 < 64 && ic + 1 < IC) hi = f2bf(x[((size_t)b * IC + ic + 1) * 196 + s]);
    ((unsigned int*)xt)[(size_t)b * tot + idx] = lo | (hi << 16);
}

// ---------------- weight pack: w[oc][ic][27] f32 -> wp[t][oc][ic] bf16 ------
__global__ void k_wpack(const float* __restrict__ w, unsigned short* __restrict__ wp,
                        int IC) {
    int nc = IC >> 3;
    int idx = blockIdx.x * 256 + threadIdx.x;
    if (idx >= 27 * 128 * nc) return;
    int c = idx % nc; int r = idx / nc; int oc = r & 127; int t = r >> 7;
    const float* ws = w + ((size_t)oc * IC + c * 8) * 27 + t;
    unsigned int o0 = f2bf(ws[0])   | ((unsigned int)f2bf(ws[27])  << 16);
    unsigned int o1 = f2bf(ws[54])  | ((unsigned int)f2bf(ws[81])  << 16);
    unsigned int o2 = f2bf(ws[108]) | ((unsigned int)f2bf(ws[135]) << 16);
    unsigned int o3 = f2bf(ws[162]) | ((unsigned int)f2bf(ws[189]) << 16);
    uint4 v; v.x = o0; v.y = o1; v.z = o2; v.w = o3;
    ((uint4*)wp)[idx] = v;
}

// ---------------- MFMA conv, ic-chunk blocks ----------------
// Block = (g ic-chunk, nh oc-half, mh m-half, b). LDS = one 208x72 bf16 chunk.
// Wave: 2 M-tiles x 4 N-tiles, 27 taps x 2 k-slices.
template <int IC, int G>
__global__ __launch_bounds__(256, 2) void k_convchunk(
    const unsigned short* __restrict__ xt, const unsigned short* __restrict__ wp,
    float* __restrict__ part) {
    __shared__ unsigned short xs[208 * 72];
    const int tid = threadIdx.x;
    const int bx = blockIdx.x, b = blockIdx.y;
    const int mh = bx & 1, nh = (bx >> 1) & 1, g = bx >> 2;

    {
        const bf16x8* s8 = (const bf16x8*)(xt + ((size_t)b * G + g) * (208 * 72));
        bf16x8* d8 = (bf16x8*)xs;
        for (int c = tid; c < 208 * 72 / 8; c += 256) d8[c] = s8[c];
    }
    __syncthreads();

    const int lane = tid & 63, wv = tid >> 6;
    const int a = lane & 15, kg = lane >> 4;

    int md[2], mhh[2], mw[2];
#pragma unroll
    for (int i = 0; i < 2; ++i) {
        int m = (mh * 8 + wv * 2 + i) * 16 + a;
        md[i] = m / 49; int rr = m - md[i] * 49;
        mhh[i] = rr / 7; mw[i] = rr - mhh[i] * 7;
    }

    f32x4 acc[2][4];
#pragma unroll
    for (int i = 0; i < 2; ++i)
#pragma unroll
        for (int nt = 0; nt < 4; ++nt) acc[i][nt] = (f32x4){0.f, 0.f, 0.f, 0.f};

    const bf16x8 zv = {0, 0, 0, 0, 0, 0, 0, 0};
    for (int t = 0; t < 27; ++t) {
        int kd = t / 9, kh = (t / 3) % 3, kw = t % 3;
        int rsrc[2]; bool ok[2];
#pragma unroll
        for (int i = 0; i < 2; ++i) {
            int d2 = md[i] + kd - 1, h2 = mhh[i] + kh - 1, w2 = mw[i] + kw - 1;
            ok[i] = ((unsigned)d2 < 4u) & ((unsigned)h2 < 7u) & ((unsigned)w2 < 7u);
            rsrc[i] = ok[i] ? (d2 * 49 + h2 * 7 + w2) : 0;
        }
        const unsigned short* wrow = wp + ((size_t)t * 128 + nh * 64 + a) * IC + g * 64;
#pragma unroll
        for (int kk = 0; kk < 2; ++kk) {
            int kb = kk * 32 + kg * 8;
            bf16x8 A[2];
#pragma unroll
            for (int i = 0; i < 2; ++i) {
                bf16x8 v = *(const bf16x8*)(xs + rsrc[i] * 72 + kb);
                A[i] = ok[i] ? v : zv;
            }
#pragma unroll
            for (int nt = 0; nt < 4; ++nt) {
                bf16x8 B = *(const bf16x8*)(wrow + (size_t)nt * 16 * IC + kb);
#pragma unroll
                for (int i = 0; i < 2; ++i)
                    acc[i][nt] = __builtin_amdgcn_mfma_f32_16x16x32_bf16(A[i], B, acc[i][nt], 0, 0, 0);
            }
        }
    }

    float* dst = part + ((size_t)g * 32 + b) * (128 * 196);
#pragma unroll
    for (int i = 0; i < 2; ++i) {
        int m0 = (mh * 8 + wv * 2 + i) * 16 + kg * 4;
        if (m0 < 196) {
#pragma unroll
            for (int nt = 0; nt < 4; ++nt) {
                int oc = nh * 64 + nt * 16 + a;
                *(f32x4*)(dst + (size_t)oc * 196 + m0) = acc[i][nt];
            }
        }
    }
}

// sum G partials
template <int G>
__global__ void k_reduceG(const float* __restrict__ part, float* __restrict__ y, int n) {
    int i = blockIdx.x * blockDim.x + threadIdx.x;
    if (i < n) {
        float s = 0.f;
#pragma unroll
        for (int g = 0; g < G; ++g) s += part[(size_t)g * n + i];
        y[i] = s;
    }
}

// ---------------- transpose of 8 [196,196] matrices ----------------
struct P8 { const float* p[8]; };
__global__ void k_transpose8(P8 ws_in, float* __restrict__ wt) {
    int i = blockIdx.x, m = blockIdx.y;
    const float* w = ws_in.p[m];
    float* o = wt + (size_t)m * 38416;
    for (int t = threadIdx.x; t < 196; t += blockDim.x)
        o[(size_t)i * 196 + t] = w[(size_t)t * 196 + i];
}

// ---------------- BN ----------------
__global__ void k_bn_stats(const float* __restrict__ y, float* __restrict__ stats,
                           int C) {
    int ch = blockIdx.x; int tid = threadIdx.x;
    float s = 0.f, s2 = 0.f;
    for (int b = 0; b < 32; ++b) {
        const float* p = &y[(size_t)(b * C + ch) * 196];
        for (int i = tid; i < 196; i += 256) { float v = p[i]; s += v; s2 += v * v; }
    }
    __shared__ float r1[4], r2[4];
    for (int sh = 32; sh; sh >>= 1) { s += __shfl_xor(s, sh); s2 += __shfl_xor(s2, sh); }
    if ((tid & 63) == 0) { r1[tid >> 6] = s; r2[tid >> 6] = s2; }
    __syncthreads();
    if (tid == 0) {
        float S = r1[0] + r1[1] + r1[2] + r1[3];
        float S2 = r2[0] + r2[1] + r2[2] + r2[3];
        float m = S / 6272.f;
        float v = S2 / 6272.f - m * m;
        stats[2 * ch] = m;
        stats[2 * ch + 1] = rsqrtf(v + 1e-5f);
    }
}

__global__ void k_bn_apply_relu(float* __restrict__ y, const float* __restrict__ stats,
                                const float* __restrict__ g, const float* __restrict__ be,
                                float* __restrict__ fT, int C) {
    int idx = blockIdx.x;
    int ch = idx % C, b = idx / C;
    int s = threadIdx.x;
    if (s < 196) {
        float m = stats[2 * ch], r = stats[2 * ch + 1];
        float v = y[(size_t)idx * 196 + s];
        float o = fmaxf((v - m) * r * g[ch] + be[ch], 0.f);
        y[(size_t)idx * 196 + s] = o;
        if (fT) fT[((size_t)b * 196 + s) * C + ch] = o;
    }
}

// ---------------- catnum ----------------
__global__ void k_catnum(const float* __restrict__ inp, int A,
                         const float* __restrict__ w, const float* __restrict__ bias,
                         const float* __restrict__ g, const float* __restrict__ be,
                         float* __restrict__ outv) {
    int j = blockIdx.x;
    int lane = threadIdx.x;
    float v = 0.f;
    if (lane < 32) {
        v = bias[j];
        for (int k = 0; k < A; ++k) v += inp[lane * A + k] * w[j * A + k];
    }
    float s = (lane < 32) ? v : 0.f;
    float s2 = (lane < 32) ? v * v : 0.f;
    for (int m = 16; m; m >>= 1) { s += __shfl_xor(s, m, 32); s2 += __shfl_xor(s2, m, 32); }
    if (lane < 32) {
        float mean = s / 32.f;
        float var = s2 / 32.f - mean * mean;
        float rstd = rsqrtf(var + 1e-5f);
        float t = (v - mean) * rstd * g[j] + be[j];
        t = t / (1.f + expf(-t));
        outv[lane * 196 + j] = t;
    }
}

__global__ void k_textbuild(const float* __restrict__ toh, const float* __restrict__ tnm,
                            float* __restrict__ text, float* __restrict__ textT) {
    int idx = blockIdx.x;
    int b = idx / 45, c = idx - b * 45;
    int s = threadIdx.x;
    if (s < 196) {
        float v = (c < 30) ? toh[b * 196 + s] : tnm[b * 196 + s];
        text[(size_t)idx * 196 + s] = v;
        textT[((size_t)b * 196 + s) * 45 + c] = v;
    }
}

// ---------------- GCN dist (multi-row) ----------------
template <int C, int ROWS>
__global__ void k_gcn_dist_t(const float* __restrict__ f, const float* __restrict__ fT,
                             float* __restrict__ dist) {
    __shared__ float fi[ROWS][196];
    const int i0 = blockIdx.x * ROWS, b = blockIdx.y;
    const int tid = threadIdx.x;
    for (int idx = tid; idx < ROWS * 196; idx += 256) {
        int r = idx / 196, n = idx - r * 196;
        fi[r][n] = f[((size_t)(b * C + i0 + r)) * 196 + n];
    }
    __syncthreads();
    if (tid < C) {
        const float* ft = fT + (size_t)b * 196 * C + tid;
        float a[ROWS];
#pragma unroll
        for (int r = 0; r < ROWS; ++r) a[r] = 0.f;
#pragma unroll 4
        for (int n = 0; n < 196; ++n) {
            float v = ft[(size_t)n * C];
#pragma unroll
            for (int r = 0; r < ROWS; ++r) a[r] += fabsf(fi[r][n] - v);
        }
#pragma unroll
        for (int r = 0; r < ROWS; ++r)
            dist[((size_t)(b * C + i0 + r)) * C + tid] = expf(-a[r]);
    }
}

// ---------------- GCN spmm+fin (multi-row) ----------------
template <int C, int ROWS>
__global__ void k_gcn_spmmfin_t(const float* __restrict__ dist, const float* __restrict__ f,
                                const float* __restrict__ wt, const float* __restrict__ bias,
                                float* __restrict__ outp) {
    __shared__ float ds[ROWS][C];
    __shared__ float ts[ROWS][196];
    const int i0 = blockIdx.x * ROWS, b = blockIdx.y;
    const int tid = threadIdx.x;
    for (int idx = tid; idx < ROWS * C; idx += 256) {
        int r = idx / C, j = idx - r * C;
        ds[r][j] = dist[((size_t)(b * C + i0 + r)) * C + j];
    }
    __syncthreads();
    if (tid < 196) {
        float a[ROWS];
#pragma unroll
        for (int r = 0; r < ROWS; ++r) a[r] = 0.f;
#pragma unroll 4
        for (int j = 0; j < C; ++j) {
            float v = f[((size_t)b * C + j) * 196 + tid];
#pragma unroll
            for (int r = 0; r < ROWS; ++r) a[r] += ds[r][j] * v;
        }
#pragma unroll
        for (int r = 0; r < ROWS; ++r) ts[r][tid] = a[r];
    }
    __syncthreads();
    if (tid < 196) {
        float a[ROWS];
        float bi = bias[tid];
#pragma unroll
        for (int r = 0; r < ROWS; ++r) a[r] = bi;
#pragma unroll 4
        for (int n = 0; n < 196; ++n) {
            float wv = wt[(size_t)n * 196 + tid];
#pragma unroll
            for (int r = 0; r < ROWS; ++r) a[r] += ts[r][n] * wv;
        }
#pragma unroll
        for (int r = 0; r < ROWS; ++r) {
            size_t rr = ((size_t)(b * C + i0 + r)) * 196 + tid;
            outp[rr] = fmaxf(a[r], 0.f) + f[rr];
        }
    }
}

// ---------------- LN + relu(linear), multi-row, dual-layout q ----------------
template <int R, int ROWS>
__global__ void k_lnlin_t(const float* __restrict__ x, const float* __restrict__ g,
                          const float* __restrict__ be, const float* __restrict__ eT,
                          const float* __restrict__ eb, float* __restrict__ lnout,
                          float* __restrict__ qout, float* __restrict__ qT) {
    __shared__ float ls[ROWS][196];
    const int i0 = blockIdx.x * ROWS, b = blockIdx.y;
    const int tid = threadIdx.x;
    const int wv = tid >> 6, lane = tid & 63;
    for (int idx = tid; idx < ROWS * 196; idx += 256) {
        int r = idx / 196, n = idx - r * 196;
        ls[r][n] = x[((size_t)(b * R + i0 + r)) * 196 + n];
    }
    __syncthreads();
    for (int k = 0;; ++k) {
        int r = wv + 4 * k;
        if (r >= ROWS) break;
        float s = 0.f, s2 = 0.f;
        for (int j = lane; j < 196; j += 64) { float v = ls[r][j]; s += v; s2 += v * v; }
        for (int sh = 32; sh; sh >>= 1) { s += __shfl_xor(s, sh); s2 += __shfl_xor(s2, sh); }
        float mean = s / 196.f;
        float var = s2 / 196.f - mean * mean;
        float rstd = rsqrtf(var + 1e-6f);
        size_t rowo = ((size_t)(b * R + i0 + r)) * 196;
        for (int j = lane; j < 196; j += 64) {
            float l = (ls[r][j] - mean) * rstd * g[j] + be[j];
            ls[r][j] = l;
            lnout[rowo + j] = l;
        }
    }
    __syncthreads();
    if (tid < 196) {
        float a[ROWS];
        float bi = eb[tid];
#pragma unroll
        for (int r = 0; r < ROWS; ++r) a[r] = bi;
#pragma unroll 4
        for (int n = 0; n < 196; ++n) {
            float ev = eT[(size_t)n * 196 + tid];
#pragma unroll
            for (int r = 0; r < ROWS; ++r) a[r] += ls[r][n] * ev;
        }
#pragma unroll
        for (int r = 0; r < ROWS; ++r) {
            float q = fmaxf(a[r], 0.f);
            qout[((size_t)(b * R + i0 + r)) * 196 + tid] = q;
            qT[((size_t)b * 196 + tid) * R + i0 + r] = q;
        }
    }
}

// ---------------- fused cross-attention, multi-row, de-diverged ------------
template <int ROWS, int RA, int RB>
__global__ void k_attrow_t(const float* __restrict__ own, const float* __restrict__ ownT,
                           const float* __restrict__ oth, const float* __restrict__ othT,
                           const float* __restrict__ wAT, const float* __restrict__ bA,
                           const float* __restrict__ wBT, const float* __restrict__ bB,
                           const float* __restrict__ lnres, const float* __restrict__ res2,
                           float* __restrict__ feat, int cbase) {
    __shared__ float buf1[ROWS][196];      // qs -> fA
    __shared__ float sc[ROWS][176];        // scores -> probs (RA+RB=173)
    __shared__ float fB[ROWS][196];
    const int i0 = blockIdx.x * ROWS, b = blockIdx.y;
    const int tid = threadIdx.x;
    const int wv = tid >> 6, lane = tid & 63;
    const float* ownb = own + (size_t)b * RA * 196;
    const float* othb = oth + (size_t)b * RB * 196;
    for (int idx = tid; idx < ROWS * 196; idx += 256) {
        int r = idx / 196, n = idx - r * 196;
        buf1[r][n] = ownb[(size_t)(i0 + r) * 196 + n];
    }
    __syncthreads();
    {
        const bool act = tid < RA + RB;
        const float* ptr = nullptr;
        int stride = 1;
        if (act) {
            if (tid < RA) { ptr = ownT + (size_t)b * 196 * RA + tid; stride = RA; }
            else          { ptr = othT + (size_t)b * 196 * RB + (tid - RA); stride = RB; }
        }
        if (act) {
            float a[ROWS];
#pragma unroll
            for (int r = 0; r < ROWS; ++r) a[r] = 0.f;
#pragma unroll 4
            for (int n = 0; n < 196; ++n) {
                float kv = ptr[(size_t)n * stride];
#pragma unroll
                for (int r = 0; r < ROWS; ++r) a[r] += buf1[r][n] * kv;
            }
#pragma unroll
            for (int r = 0; r < ROWS; ++r) sc[r][tid] = a[r];
        }
    }
    __syncthreads();
    for (int k = 0;; ++k) {
        int r = wv + 4 * k;
        if (r >= ROWS) break;
        softseg(&sc[r][0], RA, lane);
        softseg(&sc[r][RA], RB, lane);
    }
    __syncthreads();
    if (tid < 196) {
        float a[ROWS];
#pragma unroll
        for (int r = 0; r < ROWS; ++r) a[r] = 0.f;
#pragma unroll 4
        for (int j = 0; j < RA; ++j) {
            float v = ownb[(size_t)j * 196 + tid];
#pragma unroll
            for (int r = 0; r < ROWS; ++r) a[r] += sc[r][j] * v;
        }
        float c[ROWS];
#pragma unroll
        for (int r = 0; r < ROWS; ++r) c[r] = 0.f;
#pragma unroll 4
        for (int j = 0; j < RB; ++j) {
            float v = othb[(size_t)j * 196 + tid];
#pragma unroll
            for (int r = 0; r < ROWS; ++r) c[r] += sc[r][RA + j] * v;
        }
#pragma unroll
        for (int r = 0; r < ROWS; ++r) { buf1[r][tid] = a[r]; fB[r][tid] = c[r]; }
    }
    __syncthreads();
    if (tid < 196) {
        float a[ROWS];
        float bb = bA[tid] + bB[tid];
#pragma unroll
        for (int r = 0; r < ROWS; ++r) {
            size_t rr = ((size_t)(b * RA + i0 + r)) * 196 + tid;
            a[r] = bb + lnres[rr] + res2[rr];
        }
#pragma unroll 4
        for (int n = 0; n < 196; ++n) {
            float wa = wAT[(size_t)n * 196 + tid];
            float wb = wBT[(size_t)n * 196 + tid];
#pragma unroll
            for (int r = 0; r < ROWS; ++r) a[r] += buf1[r][n] * wa + fB[r][n] * wb;
        }
#pragma unroll
        for (int r = 0; r < ROWS; ++r)
            feat[((size_t)(b * 173 + cbase + i0 + r)) * 196 + tid] = a[r];
    }
}

// ---------------- 1x1 conv, multi-row; RES=0 writes qT, RES=1 res+rowsum ----
template <int RES, int ROWS>
__global__ void k_conv1x1_t(const float* __restrict__ x, const float* __restrict__ w,
                            const float* __restrict__ bias, const float* __restrict__ res,
                            float* __restrict__ outp, float* __restrict__ aux) {
    __shared__ float wsm[ROWS][173];
    __shared__ float vals[ROWS][200];
    const int o0 = blockIdx.x * ROWS, b = blockIdx.y;
    const int tid = threadIdx.x;
    const int nv = (173 - o0 < ROWS) ? (173 - o0) : ROWS;
    for (int idx = tid; idx < nv * 173; idx += 256) {
        int r = idx / 173, c = idx - r * 173;
        wsm[r][c] = w[(size_t)(o0 + r) * 173 + c];
    }
    __syncthreads();
    if (tid < 196) {
        float a[ROWS];
#pragma unroll
        for (int r = 0; r < ROWS; ++r) a[r] = (r < nv) ? bias[o0 + r] : 0.f;
#pragma unroll 4
        for (int c = 0; c < 173; ++c) {
            float xv = x[((size_t)(b * 173 + c)) * 196 + tid];
#pragma unroll
            for (int r = 0; r < ROWS; ++r) a[r] += wsm[r][c] * xv;
        }
#pragma unroll
        for (int r = 0; r < ROWS; ++r) {
            if (r < nv) {
                float v = fmaxf(a[r], 0.f);
                size_t rr = ((size_t)(b * 173 + o0 + r)) * 196 + tid;
                if (RES) v += res[rr];
                outp[rr] = v;
                if (!RES) aux[((size_t)b * 196 + tid) * 173 + o0 + r] = v;
                if (RES) vals[r][tid] = v;
            }
        }
    }
    if (RES) {
        __syncthreads();
        int wv = tid >> 6, lane = tid & 63;
        for (int k = 0;; ++k) {
            int r = wv + 4 * k;
            if (r >= nv) break;
            float s = 0.f;
            for (int j = lane; j < 196; j += 64) s += vals[r][j];
            for (int sh = 32; sh; sh >>= 1) s += __shfl_xor(s, sh);
            if (lane == 0) aux[(size_t)b * 173 + o0 + r] = s;
        }
    }
}

// ---------------- CMSA attention (multi-row, writes A^T) ----------------
template <int ROWS>
__global__ void k_cmsa_att_t(const float* __restrict__ q, const float* __restrict__ qT,
                             float* __restrict__ AT) {
    __shared__ float colt[ROWS][176];
    __shared__ float sc[ROWS][200];
    const int i0 = blockIdx.x * ROWS, b = blockIdx.y;
    const int tid = threadIdx.x;
    for (int idx = tid; idx < ROWS * 173; idx += 256) {
        int r = idx / 173, c = idx - r * 173;
        colt[r][c] = qT[((size_t)b * 196 + i0 + r) * 173 + c];
    }
    __syncthreads();
    if (tid < 196) {
        float a[ROWS];
#pragma unroll
        for (int r = 0; r < ROWS; ++r) a[r] = 0.f;
#pragma unroll 4
        for (int c = 0; c < 173; ++c) {
            float qv = q[((size_t)(b * 173 + c)) * 196 + tid];
#pragma unroll
            for (int r = 0; r < ROWS; ++r) a[r] += colt[r][c] * qv;
        }
#pragma unroll
        for (int r = 0; r < ROWS; ++r) sc[r][tid] = a[r];
    }
    __syncthreads();
    int wv = tid >> 6, lane = tid & 63;
    for (int k = 0;; ++k) {
        int r = wv + 4 * k;
        if (r >= ROWS) break;
        softseg(&sc[r][0], 196, lane);
    }
    __syncthreads();
    for (int idx = tid; idx < ROWS * 196; idx += 256) {
        int r = idx / 196, j = idx - r * 196;
        AT[((size_t)b * 196 + j) * 196 + i0 + r] = sc[r][j];
    }
}

// ---------------- CMSA apply (multi-row) ----------------
template <int ROWS>
__global__ void k_cmsa_apply_t(const float* __restrict__ AT, const float* __restrict__ q,
                               float* __restrict__ fea) {
    __shared__ float qsr[ROWS][196];
    const int c0 = blockIdx.x * ROWS, b = blockIdx.y;
    const int tid = threadIdx.x;
    const int nv = (173 - c0 < ROWS) ? (173 - c0) : ROWS;
    for (int idx = tid; idx < nv * 196; idx += 256) {
        int r = idx / 196, n = idx - r * 196;
        qsr[r][n] = q[((size_t)(b * 173 + c0 + r)) * 196 + n];
    }
    __syncthreads();
    if (tid < 196) {
        float a[ROWS];
#pragma unroll
        for (int r = 0; r < ROWS; ++r) a[r] = 0.f;
        const float* at = AT + (size_t)b * 196 * 196 + tid;
#pragma unroll 4
        for (int j = 0; j < 196; ++j) {
            float av = at[(size_t)j * 196];
#pragma unroll
            for (int r = 0; r < ROWS; ++r) a[r] += av * qsr[r][j];
        }
#pragma unroll
        for (int r = 0; r < ROWS; ++r)
            if (r < nv) fea[((size_t)(b * 173 + c0 + r)) * 196 + tid] = a[r];
    }
}

// ---------------- final classifier ----------------
__global__ void k_finale(const float* __restrict__ toh, const float* __restrict__ tnm,
                         const float* __restrict__ rowsum, const float* __restrict__ cls_w,
                         const float* __restrict__ cls_b, float* __restrict__ out) {
    int b = blockIdx.x;
    __shared__ float r1[4], r2[4];
    int tid = threadIdx.x;
    float a = (tid < 196) ? toh[b * 196 + tid] : 0.f;
    float c = (tid < 196) ? tnm[b * 196 + tid] : 0.f;
    for (int sh = 32; sh; sh >>= 1) { a += __shfl_xor(a, sh); c += __shfl_xor(c, sh); }
    if ((tid & 63) == 0) { r1[tid >> 6] = a; r2[tid >> 6] = c; }
    __syncthreads();
    if (tid < 2) {
        float soh = r1[0] + r1[1] + r1[2] + r1[3];
        float snm = r2[0] + r2[1] + r2[2] + r2[3];
        const float* wrow = &cls_w[tid * 218];
        float acc = cls_b[tid];
        float w1 = 0.f, w2 = 0.f;
        for (int k = 0; k < 30; ++k) w1 += wrow[k];
        for (int k = 30; k < 45; ++k) w2 += wrow[k];
        acc += soh * w1 + snm * w2;
        for (int k = 0; k < 173; ++k) acc += wrow[45 + k] * rowsum[(size_t)b * 173 + k];
        out[b * 2 + tid] = acc;
    }
}

// ---------------------------------------------------------------------------
extern "C" void kernel_launch(void* const* d_in, const int* in_sizes, int n_in,
                              void* d_out, int out_size, void* d_ws, size_t ws_size,
                              hipStream_t stream) {
    const float* x      = (const float*)d_in[0];
    const float* oneHot = (const float*)d_in[1];
    const float* num    = (const float*)d_in[2];
    const float* c1_w1  = (const float*)d_in[3];
    const float* c1_g1  = (const float*)d_in[5];
    const float* c1_be1 = (const float*)d_in[6];
    const float* c1_w2  = (const float*)d_in[7];
    const float* c1_g2  = (const float*)d_in[9];
    const float* c1_be2 = (const float*)d_in[10];
    const float* oh_w   = (const float*)d_in[11];
    const float* oh_b   = (const float*)d_in[12];
    const float* oh_g   = (const float*)d_in[13];
    const float* oh_be  = (const float*)d_in[14];
    const float* nm_w   = (const float*)d_in[15];
    const float* nm_b   = (const float*)d_in[16];
    const float* nm_g   = (const float*)d_in[17];
    const float* nm_be  = (const float*)d_in[18];
    const float* gm1_w  = (const float*)d_in[19];
    const float* gm1_b  = (const float*)d_in[20];
    const float* gm2_w  = (const float*)d_in[21];
    const float* gm2_b  = (const float*)d_in[22];
    const float* ln1_g  = (const float*)d_in[23];
    const float* ln1_b  = (const float*)d_in[24];
    const float* ln2_g  = (const float*)d_in[25];
    const float* ln2_b  = (const float*)d_in[26];
    const float* e1_w   = (const float*)d_in[27];
    const float* e1_b   = (const float*)d_in[28];
    const float* e2_w   = (const float*)d_in[29];
    const float* e2_b   = (const float*)d_in[30];
    const float* f1_w   = (const float*)d_in[31];
    const float* f1_b   = (const float*)d_in[32];
    const float* f2_w   = (const float*)d_in[33];
    const float* f2_b   = (const float*)d_in[34];
    const float* f3_w   = (const float*)d_in[35];
    const float* f3_b   = (const float*)d_in[36];
    const float* f4_w   = (const float*)d_in[37];
    const float* f4_b   = (const float*)d_in[38];
    const float* cm_w   = (const float*)d_in[39];
    const float* cm_b   = (const float*)d_in[40];
    const float* cmf_w  = (const float*)d_in[41];
    const float* cmf_b  = (const float*)d_in[42];
    const float* cls_w  = (const float*)d_in[43];
    const float* cls_b  = (const float*)d_in[44];
    float* out = (float*)d_out;
    float* W = (float*)d_ws;

    const size_t L = 802816;
    const size_t T = 282240;
    const size_t F3 = 1085056;
    const size_t o_A    = 0;
    const size_t o_B    = L;
    const size_t o_C    = 2 * L;
    const size_t o_part = 3 * L;          // conv partials [3L, 8L) (G<=5)
    const size_t o_iq   = 3 * L;
    const size_t o_tq   = 4 * L;
    const size_t o_t1   = 4 * L + T;
    const size_t o_t3   = 4 * L + 2 * T;
    const size_t o_ln2  = 4 * L + 3 * T;
    const size_t o_toh  = 4 * L + 4 * T;
    const size_t o_tnm  = o_toh + 6272;
    const size_t o_st   = o_tnm + 6272;
    const size_t o_wT   = o_st + 1024;
    const size_t o_feat = o_wT + 8 * 38416;
    const size_t o_q    = o_feat + F3;
    const size_t o_fea  = o_q + F3;
    const size_t o_Acm  = o_fea + F3;     // A^T [32,196,196]; gcn dists earlier
    const size_t o_d1   = o_Acm;
    const size_t o_d2   = o_Acm + 524288;
    // conv-phase-only buffers (chunk-major bf16):
    const size_t o_xt1 = 9 * L;                       // 32*5*208*72/2 = 1,198,080 floats
    const size_t o_xt2 = o_xt1 + 1198080;             // 32*2*208*72/2 =   479,232
    const size_t o_wp1 = o_xt2 + 479232;              // 27*128*320/2  =   552,960
    const size_t o_wp2 = o_wp1 + 552960;              // 27*128*128/2  =   221,184
    const size_t o_tr  = o_wp2 + 221184;              // = 9,676,800
    const size_t o_rs  = o_tr + F3;                   // rowsum 32*173
    // end ~= 10.77M floats = 43.1 MB

    float* part = W + o_part;
    unsigned short* xt1 = (unsigned short*)(W + o_xt1);
    unsigned short* xt2 = (unsigned short*)(W + o_xt2);
    unsigned short* wp1 = (unsigned short*)(W + o_wp1);
    unsigned short* wp2 = (unsigned short*)(W + o_wp2);
    float* gm1T = W + o_wT + 0 * 38416;
    float* gm2T = W + o_wT + 1 * 38416;
    float* e1T  = W + o_wT + 2 * 38416;
    float* e2T  = W + o_wT + 3 * 38416;
    float* f1T  = W + o_wT + 4 * 38416;
    float* f2T  = W + o_wT + 5 * 38416;
    float* f3T  = W + o_wT + 6 * 38416;
    float* f4T  = W + o_wT + 7 * 38416;

    // ---- conv prep ----
    k_wpack<<<(27 * 128 * 40 + 255) / 256, 256, 0, stream>>>(c1_w1, wp1, 320);
    k_wpack<<<(27 * 128 * 16 + 255) / 256, 256, 0, stream>>>(c1_w2, wp2, 128);
    k_xt_c<<<dim3((5 * 208 * 36 + 255) / 256, 32), 256, 0, stream>>>(x, xt1, 320, 5);

    // ---- conv1: 5 chunks x 2 nh x 2 mh -> 640 blocks ----
    k_convchunk<320, 5><<<dim3(20, 32), 256, 0, stream>>>(xt1, wp1, part);
    k_reduceG<5><<<3136, 256, 0, stream>>>(part, W + o_A, 802816);
    k_bn_stats<<<128, 256, 0, stream>>>(W + o_A, W + o_st, 128);
    k_bn_apply_relu<<<4096, 256, 0, stream>>>(W + o_A, W + o_st, c1_g1, c1_be1, nullptr, 128);

    // ---- conv2: 2 chunks x 2 x 2 -> 256 blocks ----
    k_xt_c<<<dim3((2 * 208 * 36 + 255) / 256, 32), 256, 0, stream>>>(W + o_A, xt2, 128, 2);
    k_convchunk<128, 2><<<dim3(8, 32), 256, 0, stream>>>(xt2, wp2, part);
    k_reduceG<2><<<3136, 256, 0, stream>>>(part, W + o_B, 802816);
    k_bn_stats<<<128, 256, 0, stream>>>(W + o_B, W + o_st + 512, 128);
    k_bn_apply_relu<<<4096, 256, 0, stream>>>(W + o_B, W + o_st + 512, c1_g2, c1_be2,
                                              W + o_tr, 128);

    // ---- weight transposes ----
    P8 p8;
    p8.p[0] = gm1_w; p8.p[1] = gm2_w; p8.p[2] = e1_w; p8.p[3] = e2_w;
    p8.p[4] = f1_w;  p8.p[5] = f2_w;  p8.p[6] = f3_w; p8.p[7] = f4_w;
    k_transpose8<<<dim3(196, 8), 256, 0, stream>>>(p8, W + o_wT);

    // ---- catnum / text ----
    k_catnum<<<196, 64, 0, stream>>>(oneHot, 24, oh_w, oh_b, oh_g, oh_be, W + o_toh);
    k_catnum<<<196, 64, 0, stream>>>(num, 11, nm_w, nm_b, nm_g, nm_be, W + o_tnm);
    k_textbuild<<<32 * 45, 256, 0, stream>>>(W + o_toh, W + o_tnm, W + o_t1, W + o_tr + L);

    // ---- GCN img ----
    k_gcn_dist_t<128, 4><<<dim3(32, 32), 256, 0, stream>>>(W + o_B, W + o_tr, W + o_d1);
    k_gcn_spmmfin_t<128, 4><<<dim3(32, 32), 256, 0, stream>>>(W + o_d1, W + o_B, gm1T,
                                                              gm1_b, W + o_C);
    // ---- GCN text ----
    k_gcn_dist_t<45, 3><<<dim3(15, 32), 256, 0, stream>>>(W + o_t1, W + o_tr + L, W + o_d2);
    k_gcn_spmmfin_t<45, 3><<<dim3(15, 32), 256, 0, stream>>>(W + o_d2, W + o_t1, gm2T,
                                                             gm2_b, W + o_t3);

    // ---- LN + q projections ----
    k_lnlin_t<128, 4><<<dim3(32, 32), 256, 0, stream>>>(W + o_C, ln1_g, ln1_b, e1T, e1_b,
                                                        W + o_B, W + o_iq, W + o_tr);
    k_lnlin_t<45, 3><<<dim3(15, 32), 256, 0, stream>>>(W + o_t3, ln2_g, ln2_b, e2T, e2_b,
                                                       W + o_ln2, W + o_tq, W + o_tr + L);

    // ---- cross-attention -> feat ----
    k_attrow_t<4, 128, 45><<<dim3(32, 32), 256, 0, stream>>>(
        W + o_iq, W + o_tr, W + o_tq, W + o_tr + L,
        f1T, f1_b, f3T, f3_b, W + o_B, W + o_C, W + o_feat, 0);
    k_attrow_t<3, 45, 128><<<dim3(15, 32), 256, 0, stream>>>(
        W + o_tq, W + o_tr + L, W + o_iq, W + o_tr,
        f2T, f2_b, f4T, f4_b, W + o_ln2, W + o_t3, W + o_feat, 128);

    // ---- CMSA ----
    k_conv1x1_t<0, 4><<<dim3(44, 32), 256, 0, stream>>>(W + o_feat, cm_w, cm_b, nullptr,
                                                        W + o_q, W + o_tr);
    k_cmsa_att_t<4><<<dim3(49, 32), 256, 0, stream>>>(W + o_q, W + o_tr, W + o_Acm);
    k_cmsa_apply_t<4><<<dim3(44, 32), 256, 0, stream>>>(W + o_Acm, W + o_q, W + o_fea);
    k_conv1x1_t<1, 4><<<dim3(44, 32), 256, 0, stream>>>(W + o_fea, cmf_w, cmf_b, W + o_feat,
                                                        W + o_q, W + o_rs);

    // ---- final classifier ----
    k_finale<<<32, 256, 0, stream>>>(W + o_toh, W + o_tnm, W + o_rs, cls_w, cls_b, out);
}

// Round 10
// 562.293 us; speedup vs baseline: 1.0035x; 1.0035x over previous
//
#include <hip/hip_runtime.h>
#include <hip/hip_bf16.h>

// ---------------------------------------------------------------------------
// mv3Dunet_down_text_cmsa forward. Round 10: conv kernel gets an explicit
// 2-deep register pipeline (prefetch A/B for tap t+1 during MFMAs of tap t)
// with named ping-pong buffers; conv2 N-split widened (512 blocks).
// Tail identical to round 9.
// ---------------------------------------------------------------------------

using bf16x8 = __attribute__((ext_vector_type(8))) short;
using f32x4  = __attribute__((ext_vector_type(4))) float;

__device__ __forceinline__ unsigned short f2bf(float f) {
    unsigned int u = __float_as_uint(f);
    u += 0x7FFFu + ((u >> 16) & 1u);
    return (unsigned short)(u >> 16);
}

// in-place softmax over s[0..len) using one wave's 64 lanes
__device__ __forceinline__ void softseg(float* s, int len, int lane) {
    float m = -3.4e38f;
    for (int j = lane; j < len; j += 64) m = fmaxf(m, s[j]);
    for (int sh = 32; sh; sh >>= 1) m = fmaxf(m, __shfl_xor(m, sh));
    float sum = 0.f;
    for (int j = lane; j < len; j += 64) { float e = expf(s[j] - m); s[j] = e; sum += e; }
    for (int sh = 32; sh; sh >>= 1) sum += __shfl_xor(sum, sh);
    float inv = 1.f / sum;
    for (int j = lane; j < len; j += 64) s[j] *= inv;
}

// ---------------- X -> chunk-major bf16: xt[b][g][208][72] ----------------
__global__ void k_xt_c(const float* __restrict__ x, unsigned short* __restrict__ xt,
                       int IC, int G) {
    int b = blockIdx.y;
    int tot = G * 208 * 36;                  // uint writes
    int idx = blockIdx.x * 256 + threadIdx.x;
    if (idx >= tot) return;
    int g = idx / (208 * 36); int r = idx - g * 208 * 36;
    int s = r / 36, cp = r - s * 36;
    int cc = cp * 2;
    int ic = g * 64 + cc;
    unsigned int lo = 0, hi = 0;
    if (s < 196 && cc < 64 && ic < IC)         lo = f2bf(x[((size_t)b * IC + ic) * 196 + s]);
    if (s < 196 && cc + 1 < 64 && ic + 1 < IC) hi = f2bf(x[((size_t)b * IC + ic + 1) * 196 + s]);
    ((unsigned int*)xt)[(size_t)b * tot + idx] = lo | (hi << 16);
}

// ---------------- weight pack: w[oc][ic][27] f32 -> wp[t][oc][ic] bf16 ------
__global__ void k_wpack(const float* __restrict__ w, unsigned short* __restrict__ wp,
                        int IC) {
    int nc = IC >> 3;
    int idx = blockIdx.x * 256 + threadIdx.x;
    if (idx >= 27 * 128 * nc) return;
    int c = idx % nc; int r = idx / nc; int oc = r & 127; int t = r >> 7;
    const float* ws = w + ((size_t)oc * IC + c * 8) * 27 + t;
    unsigned int o0 = f2bf(ws[0])   | ((unsigned int)f2bf(ws[27])  << 16);
    unsigned int o1 = f2bf(ws[54])  | ((unsigned int)f2bf(ws[81])  << 16);
    unsigned int o2 = f2bf(ws[108]) | ((unsigned int)f2bf(ws[135]) << 16);
    unsigned int o3 = f2bf(ws[162]) | ((unsigned int)f2bf(ws[189]) << 16);
    uint4 v; v.x = o0; v.y = o1; v.z = o2; v.w = o3;
    ((uint4*)wp)[idx] = v;
}

// ---------------- MFMA conv, ic-chunk blocks + 2-deep register pipeline -----
// Block = (g ic-chunk, nh N-slice of NT*16 oc, mh m-half, b).
// LDS = one 208x72 bf16 chunk. Prefetch A(t+1)/B(t+1) while MFMA'ing tap t.
template <int IC, int G, int NT, int NH>
__global__ __launch_bounds__(256, 3) void k_convchunk2(
    const unsigned short* __restrict__ xt, const unsigned short* __restrict__ wp,
    float* __restrict__ part) {
    __shared__ unsigned short xs[208 * 72];
    const int tid = threadIdx.x;
    const int bx = blockIdx.x, b = blockIdx.y;
    const int mh = bx & 1;
    const int nh = (bx >> 1) % NH;
    const int g  = (bx >> 1) / NH;

    {
        const bf16x8* s8 = (const bf16x8*)(xt + ((size_t)b * G + g) * (208 * 72));
        bf16x8* d8 = (bf16x8*)xs;
        for (int c = tid; c < 208 * 72 / 8; c += 256) d8[c] = s8[c];
    }
    __syncthreads();

    const int lane = tid & 63, wv = tid >> 6;
    const int a = lane & 15, kg = lane >> 4;

    int md[2], mhh[2], mw[2];
#pragma unroll
    for (int i = 0; i < 2; ++i) {
        int m = (mh * 8 + wv * 2 + i) * 16 + a;
        md[i] = m / 49; int rr = m - md[i] * 49;
        mhh[i] = rr / 7; mw[i] = rr - mhh[i] * 7;
    }

    f32x4 acc[2][NT];
#pragma unroll
    for (int i = 0; i < 2; ++i)
#pragma unroll
        for (int nt = 0; nt < NT; ++nt) acc[i][nt] = (f32x4){0.f, 0.f, 0.f, 0.f};

    const bf16x8 zv = {0, 0, 0, 0, 0, 0, 0, 0};
    const unsigned short* wbase = wp + ((size_t)(nh * NT * 16 + a)) * IC + g * 64 + kg * 8;

    auto loadB = [&](int t, bf16x8 (&Bv)[2][NT]) {
        const unsigned short* wr = wbase + (size_t)t * 128 * IC;
#pragma unroll
        for (int kk = 0; kk < 2; ++kk)
#pragma unroll
            for (int nt = 0; nt < NT; ++nt)
                Bv[kk][nt] = *(const bf16x8*)(wr + (size_t)nt * 16 * IC + kk * 32);
    };
    auto loadA = [&](int t, bf16x8 (&Av)[2][2]) {
        int kd = t / 9, kh = (t / 3) % 3, kw = t % 3;
#pragma unroll
        for (int i = 0; i < 2; ++i) {
            int d2 = md[i] + kd - 1, h2 = mhh[i] + kh - 1, w2 = mw[i] + kw - 1;
            bool ok = ((unsigned)d2 < 4u) & ((unsigned)h2 < 7u) & ((unsigned)w2 < 7u);
            int rs = ok ? (d2 * 49 + h2 * 7 + w2) : 0;
#pragma unroll
            for (int kk = 0; kk < 2; ++kk) {
                bf16x8 v = *(const bf16x8*)(xs + rs * 72 + kk * 32 + kg * 8);
                Av[kk][i] = ok ? v : zv;
            }
        }
    };
    auto domfma = [&](bf16x8 (&Av)[2][2], bf16x8 (&Bv)[2][NT]) {
#pragma unroll
        for (int kk = 0; kk < 2; ++kk)
#pragma unroll
            for (int nt = 0; nt < NT; ++nt)
#pragma unroll
                for (int i = 0; i < 2; ++i)
                    acc[i][nt] = __builtin_amdgcn_mfma_f32_16x16x32_bf16(
                        Av[kk][i], Bv[kk][nt], acc[i][nt], 0, 0, 0);
    };

    bf16x8 A0[2][2], A1[2][2], B0[2][NT], B1[2][NT];
    loadA(0, A0); loadB(0, B0);
    for (int tt = 0; tt < 13; ++tt) {
        int t = 2 * tt;
        loadA(t + 1, A1); loadB(t + 1, B1);      // prefetch odd tap
        domfma(A0, B0);                          // compute even tap
        loadA(t + 2, A0); loadB(t + 2, B0);      // prefetch next even tap (<=26)
        domfma(A1, B1);                          // compute odd tap
    }
    domfma(A0, B0);                              // tap 26

    float* dst = part + ((size_t)g * 32 + b) * (128 * 196);
#pragma unroll
    for (int i = 0; i < 2; ++i) {
        int m0 = (mh * 8 + wv * 2 + i) * 16 + kg * 4;
        if (m0 < 196) {
#pragma unroll
            for (int nt = 0; nt < NT; ++nt) {
                int oc = nh * NT * 16 + nt * 16 + a;
                *(f32x4*)(dst + (size_t)oc * 196 + m0) = acc[i][nt];
            }
        }
    }
}

// sum G partials
template <int G>
__global__ void k_reduceG(const float* __restrict__ part, float* __restrict__ y, int n) {
    int i = blockIdx.x * blockDim.x + threadIdx.x;
    if (i < n) {
        float s = 0.f;
#pragma unroll
        for (int g = 0; g < G; ++g) s += part[(size_t)g * n + i];
        y[i] = s;
    }
}

// ---------------- transpose of 8 [196,196] matrices ----------------
struct P8 { const float* p[8]; };
__global__ void k_transpose8(P8 ws_in, float* __restrict__ wt) {
    int i = blockIdx.x, m = blockIdx.y;
    const float* w = ws_in.p[m];
    float* o = wt + (size_t)m * 38416;
    for (int t = threadIdx.x; t < 196; t += blockDim.x)
        o[(size_t)i * 196 + t] = w[(size_t)t * 196 + i];
}

// ---------------- BN ----------------
__global__ void k_bn_stats(const float* __restrict__ y, float* __restrict__ stats,
                           int C) {
    int ch = blockIdx.x; int tid = threadIdx.x;
    float s = 0.f, s2 = 0.f;
    for (int b = 0; b < 32; ++b) {
        const float* p = &y[(size_t)(b * C + ch) * 196];
        for (int i = tid; i < 196; i += 256) { float v = p[i]; s += v; s2 += v * v; }
    }
    __shared__ float r1[4], r2[4];
    for (int sh = 32; sh; sh >>= 1) { s += __shfl_xor(s, sh); s2 += __shfl_xor(s2, sh); }
    if ((tid & 63) == 0) { r1[tid >> 6] = s; r2[tid >> 6] = s2; }
    __syncthreads();
    if (tid == 0) {
        float S = r1[0] + r1[1] + r1[2] + r1[3];
        float S2 = r2[0] + r2[1] + r2[2] + r2[3];
        float m = S / 6272.f;
        float v = S2 / 6272.f - m * m;
        stats[2 * ch] = m;
        stats[2 * ch + 1] = rsqrtf(v + 1e-5f);
    }
}

__global__ void k_bn_apply_relu(float* __restrict__ y, const float* __restrict__ stats,
                                const float* __restrict__ g, const float* __restrict__ be,
                                float* __restrict__ fT, int C) {
    int idx = blockIdx.x;
    int ch = idx % C, b = idx / C;
    int s = threadIdx.x;
    if (s < 196) {
        float m = stats[2 * ch], r = stats[2 * ch + 1];
        float v = y[(size_t)idx * 196 + s];
        float o = fmaxf((v - m) * r * g[ch] + be[ch], 0.f);
        y[(size_t)idx * 196 + s] = o;
        if (fT) fT[((size_t)b * 196 + s) * C + ch] = o;
    }
}

// ---------------- catnum ----------------
__global__ void k_catnum(const float* __restrict__ inp, int A,
                         const float* __restrict__ w, const float* __restrict__ bias,
                         const float* __restrict__ g, const float* __restrict__ be,
                         float* __restrict__ outv) {
    int j = blockIdx.x;
    int lane = threadIdx.x;
    float v = 0.f;
    if (lane < 32) {
        v = bias[j];
        for (int k = 0; k < A; ++k) v += inp[lane * A + k] * w[j * A + k];
    }
    float s = (lane < 32) ? v : 0.f;
    float s2 = (lane < 32) ? v * v : 0.f;
    for (int m = 16; m; m >>= 1) { s += __shfl_xor(s, m, 32); s2 += __shfl_xor(s2, m, 32); }
    if (lane < 32) {
        float mean = s / 32.f;
        float var = s2 / 32.f - mean * mean;
        float rstd = rsqrtf(var + 1e-5f);
        float t = (v - mean) * rstd * g[j] + be[j];
        t = t / (1.f + expf(-t));
        outv[lane * 196 + j] = t;
    }
}

__global__ void k_textbuild(const float* __restrict__ toh, const float* __restrict__ tnm,
                            float* __restrict__ text, float* __restrict__ textT) {
    int idx = blockIdx.x;
    int b = idx / 45, c = idx - b * 45;
    int s = threadIdx.x;
    if (s < 196) {
        float v = (c < 30) ? toh[b * 196 + s] : tnm[b * 196 + s];
        text[(size_t)idx * 196 + s] = v;
        textT[((size_t)b * 196 + s) * 45 + c] = v;
    }
}

// ---------------- GCN dist (multi-row) ----------------
template <int C, int ROWS>
__global__ void k_gcn_dist_t(const float* __restrict__ f, const float* __restrict__ fT,
                             float* __restrict__ dist) {
    __shared__ float fi[ROWS][196];
    const int i0 = blockIdx.x * ROWS, b = blockIdx.y;
    const int tid = threadIdx.x;
    for (int idx = tid; idx < ROWS * 196; idx += 256) {
        int r = idx / 196, n = idx - r * 196;
        fi[r][n] = f[((size_t)(b * C + i0 + r)) * 196 + n];
    }
    __syncthreads();
    if (tid < C) {
        const float* ft = fT + (size_t)b * 196 * C + tid;
        float a[ROWS];
#pragma unroll
        for (int r = 0; r < ROWS; ++r) a[r] = 0.f;
#pragma unroll 4
        for (int n = 0; n < 196; ++n) {
            float v = ft[(size_t)n * C];
#pragma unroll
            for (int r = 0; r < ROWS; ++r) a[r] += fabsf(fi[r][n] - v);
        }
#pragma unroll
        for (int r = 0; r < ROWS; ++r)
            dist[((size_t)(b * C + i0 + r)) * C + tid] = expf(-a[r]);
    }
}

// ---------------- GCN spmm+fin (multi-row) ----------------
template <int C, int ROWS>
__global__ void k_gcn_spmmfin_t(const float* __restrict__ dist, const float* __restrict__ f,
                                const float* __restrict__ wt, const float* __restrict__ bias,
                                float* __restrict__ outp) {
    __shared__ float ds[ROWS][C];
    __shared__ float ts[ROWS][196];
    const int i0 = blockIdx.x * ROWS, b = blockIdx.y;
    const int tid = threadIdx.x;
    for (int idx = tid; idx < ROWS * C; idx += 256) {
        int r = idx / C, j = idx - r * C;
        ds[r][j] = dist[((size_t)(b * C + i0 + r)) * C + j];
    }
    __syncthreads();
    if (tid < 196) {
        float a[ROWS];
#pragma unroll
        for (int r = 0; r < ROWS; ++r) a[r] = 0.f;
#pragma unroll 4
        for (int j = 0; j < C; ++j) {
            float v = f[((size_t)b * C + j) * 196 + tid];
#pragma unroll
            for (int r = 0; r < ROWS; ++r) a[r] += ds[r][j] * v;
        }
#pragma unroll
        for (int r = 0; r < ROWS; ++r) ts[r][tid] = a[r];
    }
    __syncthreads();
    if (tid < 196) {
        float a[ROWS];
        float bi = bias[tid];
#pragma unroll
        for (int r = 0; r < ROWS; ++r) a[r] = bi;
#pragma unroll 4
        for (int n = 0; n < 196; ++n) {
            float wv = wt[(size_t)n * 196 + tid];
#pragma unroll
            for (int r = 0; r < ROWS; ++r) a[r] += ts[r][n] * wv;
        }
#pragma unroll
        for (int r = 0; r < ROWS; ++r) {
            size_t rr = ((size_t)(b * C + i0 + r)) * 196 + tid;
            outp[rr] = fmaxf(a[r], 0.f) + f[rr];
        }
    }
}

// ---------------- LN + relu(linear), multi-row, dual-layout q ----------------
template <int R, int ROWS>
__global__ void k_lnlin_t(const float* __restrict__ x, const float* __restrict__ g,
                          const float* __restrict__ be, const float* __restrict__ eT,
                          const float* __restrict__ eb, float* __restrict__ lnout,
                          float* __restrict__ qout, float* __restrict__ qT) {
    __shared__ float ls[ROWS][196];
    const int i0 = blockIdx.x * ROWS, b = blockIdx.y;
    const int tid = threadIdx.x;
    const int wv = tid >> 6, lane = tid & 63;
    for (int idx = tid; idx < ROWS * 196; idx += 256) {
        int r = idx / 196, n = idx - r * 196;
        ls[r][n] = x[((size_t)(b * R + i0 + r)) * 196 + n];
    }
    __syncthreads();
    for (int k = 0;; ++k) {
        int r = wv + 4 * k;
        if (r >= ROWS) break;
        float s = 0.f, s2 = 0.f;
        for (int j = lane; j < 196; j += 64) { float v = ls[r][j]; s += v; s2 += v * v; }
        for (int sh = 32; sh; sh >>= 1) { s += __shfl_xor(s, sh); s2 += __shfl_xor(s2, sh); }
        float mean = s / 196.f;
        float var = s2 / 196.f - mean * mean;
        float rstd = rsqrtf(var + 1e-6f);
        size_t rowo = ((size_t)(b * R + i0 + r)) * 196;
        for (int j = lane; j < 196; j += 64) {
            float l = (ls[r][j] - mean) * rstd * g[j] + be[j];
            ls[r][j] = l;
            lnout[rowo + j] = l;
        }
    }
    __syncthreads();
    if (tid < 196) {
        float a[ROWS];
        float bi = eb[tid];
#pragma unroll
        for (int r = 0; r < ROWS; ++r) a[r] = bi;
#pragma unroll 4
        for (int n = 0; n < 196; ++n) {
            float ev = eT[(size_t)n * 196 + tid];
#pragma unroll
            for (int r = 0; r < ROWS; ++r) a[r] += ls[r][n] * ev;
        }
#pragma unroll
        for (int r = 0; r < ROWS; ++r) {
            float q = fmaxf(a[r], 0.f);
            qout[((size_t)(b * R + i0 + r)) * 196 + tid] = q;
            qT[((size_t)b * 196 + tid) * R + i0 + r] = q;
        }
    }
}

// ---------------- fused cross-attention, multi-row, de-diverged ------------
template <int ROWS, int RA, int RB>
__global__ void k_attrow_t(const float* __restrict__ own, const float* __restrict__ ownT,
                           const float* __restrict__ oth, const float* __restrict__ othT,
                           const float* __restrict__ wAT, const float* __restrict__ bA,
                           const float* __restrict__ wBT, const float* __restrict__ bB,
                           const float* __restrict__ lnres, const float* __restrict__ res2,
                           float* __restrict__ feat, int cbase) {
    __shared__ float buf1[ROWS][196];      // qs -> fA
    __shared__ float sc[ROWS][176];        // scores -> probs (RA+RB=173)
    __shared__ float fB[ROWS][196];
    const int i0 = blockIdx.x * ROWS, b = blockIdx.y;
    const int tid = threadIdx.x;
    const int wv = tid >> 6, lane = tid & 63;
    const float* ownb = own + (size_t)b * RA * 196;
    const float* othb = oth + (size_t)b * RB * 196;
    for (int idx = tid; idx < ROWS * 196; idx += 256) {
        int r = idx / 196, n = idx - r * 196;
        buf1[r][n] = ownb[(size_t)(i0 + r) * 196 + n];
    }
    __syncthreads();
    {
        const bool act = tid < RA + RB;
        const float* ptr = nullptr;
        int stride = 1;
        if (act) {
            if (tid < RA) { ptr = ownT + (size_t)b * 196 * RA + tid; stride = RA; }
            else          { ptr = othT + (size_t)b * 196 * RB + (tid - RA); stride = RB; }
        }
        if (act) {
            float a[ROWS];
#pragma unroll
            for (int r = 0; r < ROWS; ++r) a[r] = 0.f;
#pragma unroll 4
            for (int n = 0; n < 196; ++n) {
                float kv = ptr[(size_t)n * stride];
#pragma unroll
                for (int r = 0; r < ROWS; ++r) a[r] += buf1[r][n] * kv;
            }
#pragma unroll
            for (int r = 0; r < ROWS; ++r) sc[r][tid] = a[r];
        }
    }
    __syncthreads();
    for (int k = 0;; ++k) {
        int r = wv + 4 * k;
        if (r >= ROWS) break;
        softseg(&sc[r][0], RA, lane);
        softseg(&sc[r][RA], RB, lane);
    }
    __syncthreads();
    if (tid < 196) {
        float a[ROWS];
#pragma unroll
        for (int r = 0; r < ROWS; ++r) a[r] = 0.f;
#pragma unroll 4
        for (int j = 0; j < RA; ++j) {
            float v = ownb[(size_t)j * 196 + tid];
#pragma unroll
            for (int r = 0; r < ROWS; ++r) a[r] += sc[r][j] * v;
        }
        float c[ROWS];
#pragma unroll
        for (int r = 0; r < ROWS; ++r) c[r] = 0.f;
#pragma unroll 4
        for (int j = 0; j < RB; ++j) {
            float v = othb[(size_t)j * 196 + tid];
#pragma unroll
            for (int r = 0; r < ROWS; ++r) c[r] += sc[r][RA + j] * v;
        }
#pragma unroll
        for (int r = 0; r < ROWS; ++r) { buf1[r][tid] = a[r]; fB[r][tid] = c[r]; }
    }
    __syncthreads();
    if (tid < 196) {
        float a[ROWS];
        float bb = bA[tid] + bB[tid];
#pragma unroll
        for (int r = 0; r < ROWS; ++r) {
            size_t rr = ((size_t)(b * RA + i0 + r)) * 196 + tid;
            a[r] = bb + lnres[rr] + res2[rr];
        }
#pragma unroll 4
        for (int n = 0; n < 196; ++n) {
            float wa = wAT[(size_t)n * 196 + tid];
            float wb = wBT[(size_t)n * 196 + tid];
#pragma unroll
            for (int r = 0; r < ROWS; ++r) a[r] += buf1[r][n] * wa + fB[r][n] * wb;
        }
#pragma unroll
        for (int r = 0; r < ROWS; ++r)
            feat[((size_t)(b * 173 + cbase + i0 + r)) * 196 + tid] = a[r];
    }
}

// ---------------- 1x1 conv, multi-row; RES=0 writes qT, RES=1 res+rowsum ----
template <int RES, int ROWS>
__global__ void k_conv1x1_t(const float* __restrict__ x, const float* __restrict__ w,
                            const float* __restrict__ bias, const float* __restrict__ res,
                            float* __restrict__ outp, float* __restrict__ aux) {
    __shared__ float wsm[ROWS][173];
    __shared__ float vals[ROWS][200];
    const int o0 = blockIdx.x * ROWS, b = blockIdx.y;
    const int tid = threadIdx.x;
    const int nv = (173 - o0 < ROWS) ? (173 - o0) : ROWS;
    for (int idx = tid; idx < nv * 173; idx += 256) {
        int r = idx / 173, c = idx - r * 173;
        wsm[r][c] = w[(size_t)(o0 + r) * 173 + c];
    }
    __syncthreads();
    if (tid < 196) {
        float a[ROWS];
#pragma unroll
        for (int r = 0; r < ROWS; ++r) a[r] = (r < nv) ? bias[o0 + r] : 0.f;
#pragma unroll 4
        for (int c = 0; c < 173; ++c) {
            float xv = x[((size_t)(b * 173 + c)) * 196 + tid];
#pragma unroll
            for (int r = 0; r < ROWS; ++r) a[r] += wsm[r][c] * xv;
        }
#pragma unroll
        for (int r = 0; r < ROWS; ++r) {
            if (r < nv) {
                float v = fmaxf(a[r], 0.f);
                size_t rr = ((size_t)(b * 173 + o0 + r)) * 196 + tid;
                if (RES) v += res[rr];
                outp[rr] = v;
                if (!RES) aux[((size_t)b * 196 + tid) * 173 + o0 + r] = v;
                if (RES) vals[r][tid] = v;
            }
        }
    }
    if (RES) {
        __syncthreads();
        int wv = tid >> 6, lane = tid & 63;
        for (int k = 0;; ++k) {
            int r = wv + 4 * k;
            if (r >= nv) break;
            float s = 0.f;
            for (int j = lane; j < 196; j += 64) s += vals[r][j];
            for (int sh = 32; sh; sh >>= 1) s += __shfl_xor(s, sh);
            if (lane == 0) aux[(size_t)b * 173 + o0 + r] = s;
        }
    }
}

// ---------------- CMSA attention (multi-row, writes A^T) ----------------
template <int ROWS>
__global__ void k_cmsa_att_t(const float* __restrict__ q, const float* __restrict__ qT,
                             float* __restrict__ AT) {
    __shared__ float colt[ROWS][176];
    __shared__ float sc[ROWS][200];
    const int i0 = blockIdx.x * ROWS, b = blockIdx.y;
    const int tid = threadIdx.x;
    for (int idx = tid; idx < ROWS * 173; idx += 256) {
        int r = idx / 173, c = idx - r * 173;
        colt[r][c] = qT[((size_t)b * 196 + i0 + r) * 173 + c];
    }
    __syncthreads();
    if (tid < 196) {
        float a[ROWS];
#pragma unroll
        for (int r = 0; r < ROWS; ++r) a[r] = 0.f;
#pragma unroll 4
        for (int c = 0; c < 173; ++c) {
            float qv = q[((size_t)(b * 173 + c)) * 196 + tid];
#pragma unroll
            for (int r = 0; r < ROWS; ++r) a[r] += colt[r][c] * qv;
        }
#pragma unroll
        for (int r = 0; r < ROWS; ++r) sc[r][tid] = a[r];
    }
    __syncthreads();
    int wv = tid >> 6, lane = tid & 63;
    for (int k = 0;; ++k) {
        int r = wv + 4 * k;
        if (r >= ROWS) break;
        softseg(&sc[r][0], 196, lane);
    }
    __syncthreads();
    for (int idx = tid; idx < ROWS * 196; idx += 256) {
        int r = idx / 196, j = idx - r * 196;
        AT[((size_t)b * 196 + j) * 196 + i0 + r] = sc[r][j];
    }
}

// ---------------- CMSA apply (multi-row) ----------------
template <int ROWS>
__global__ void k_cmsa_apply_t(const float* __restrict__ AT, const float* __restrict__ q,
                               float* __restrict__ fea) {
    __shared__ float qsr[ROWS][196];
    const int c0 = blockIdx.x * ROWS, b = blockIdx.y;
    const int tid = threadIdx.x;
    const int nv = (173 - c0 < ROWS) ? (173 - c0) : ROWS;
    for (int idx = tid; idx < nv * 196; idx += 256) {
        int r = idx / 196, n = idx - r * 196;
        qsr[r][n] = q[((size_t)(b * 173 + c0 + r)) * 196 + n];
    }
    __syncthreads();
    if (tid < 196) {
        float a[ROWS];
#pragma unroll
        for (int r = 0; r < ROWS; ++r) a[r] = 0.f;
        const float* at = AT + (size_t)b * 196 * 196 + tid;
#pragma unroll 4
        for (int j = 0; j < 196; ++j) {
            float av = at[(size_t)j * 196];
#pragma unroll
            for (int r = 0; r < ROWS; ++r) a[r] += av * qsr[r][j];
        }
#pragma unroll
        for (int r = 0; r < ROWS; ++r)
            if (r < nv) fea[((size_t)(b * 173 + c0 + r)) * 196 + tid] = a[r];
    }
}

// ---------------- final classifier ----------------
__global__ void k_finale(const float* __restrict__ toh, const float* __restrict__ tnm,
                         const float* __restrict__ rowsum, const float* __restrict__ cls_w,
                         const float* __restrict__ cls_b, float* __restrict__ out) {
    int b = blockIdx.x;
    __shared__ float r1[4], r2[4];
    int tid = threadIdx.x;
    float a = (tid < 196) ? toh[b * 196 + tid] : 0.f;
    float c = (tid < 196) ? tnm[b * 196 + tid] : 0.f;
    for (int sh = 32; sh; sh >>= 1) { a += __shfl_xor(a, sh); c += __shfl_xor(c, sh); }
    if ((tid & 63) == 0) { r1[tid >> 6] = a; r2[tid >> 6] = c; }
    __syncthreads();
    if (tid < 2) {
        float soh = r1[0] + r1[1] + r1[2] + r1[3];
        float snm = r2[0] + r2[1] + r2[2] + r2[3];
        const float* wrow = &cls_w[tid * 218];
        float acc = cls_b[tid];
        float w1 = 0.f, w2 = 0.f;
        for (int k = 0; k < 30; ++k) w1 += wrow[k];
        for (int k = 30; k < 45; ++k) w2 += wrow[k];
        acc += soh * w1 + snm * w2;
        for (int k = 0; k < 173; ++k) acc += wrow[45 + k] * rowsum[(size_t)b * 173 + k];
        out[b * 2 + tid] = acc;
    }
}

// ---------------------------------------------------------------------------
extern "C" void kernel_launch(void* const* d_in, const int* in_sizes, int n_in,
                              void* d_out, int out_size, void* d_ws, size_t ws_size,
                              hipStream_t stream) {
    const float* x      = (const float*)d_in[0];
    const float* oneHot = (const float*)d_in[1];
    const float* num    = (const float*)d_in[2];
    const float* c1_w1  = (const float*)d_in[3];
    const float* c1_g1  = (const float*)d_in[5];
    const float* c1_be1 = (const float*)d_in[6];
    const float* c1_w2  = (const float*)d_in[7];
    const float* c1_g2  = (const float*)d_in[9];
    const float* c1_be2 = (const float*)d_in[10];
    const float* oh_w   = (const float*)d_in[11];
    const float* oh_b   = (const float*)d_in[12];
    const float* oh_g   = (const float*)d_in[13];
    const float* oh_be  = (const float*)d_in[14];
    const float* nm_w   = (const float*)d_in[15];
    const float* nm_b   = (const float*)d_in[16];
    const float* nm_g   = (const float*)d_in[17];
    const float* nm_be  = (const float*)d_in[18];
    const float* gm1_w  = (const float*)d_in[19];
    const float* gm1_b  = (const float*)d_in[20];
    const float* gm2_w  = (const float*)d_in[21];
    const float* gm2_b  = (const float*)d_in[22];
    const float* ln1_g  = (const float*)d_in[23];
    const float* ln1_b  = (const float*)d_in[24];
    const float* ln2_g  = (const float*)d_in[25];
    const float* ln2_b  = (const float*)d_in[26];
    const float* e1_w   = (const float*)d_in[27];
    const float* e1_b   = (const float*)d_in[28];
    const float* e2_w   = (const float*)d_in[29];
    const float* e2_b   = (const float*)d_in[30];
    const float* f1_w   = (const float*)d_in[31];
    const float* f1_b   = (const float*)d_in[32];
    const float* f2_w   = (const float*)d_in[33];
    const float* f2_b   = (const float*)d_in[34];
    const float* f3_w   = (const float*)d_in[35];
    const float* f3_b   = (const float*)d_in[36];
    const float* f4_w   = (const float*)d_in[37];
    const float* f4_b   = (const float*)d_in[38];
    const float* cm_w   = (const float*)d_in[39];
    const float* cm_b   = (const float*)d_in[40];
    const float* cmf_w  = (const float*)d_in[41];
    const float* cmf_b  = (const float*)d_in[42];
    const float* cls_w  = (const float*)d_in[43];
    const float* cls_b  = (const float*)d_in[44];
    float* out = (float*)d_out;
    float* W = (float*)d_ws;

    const size_t L = 802816;
    const size_t T = 282240;
    const size_t F3 = 1085056;
    const size_t o_A    = 0;
    const size_t o_B    = L;
    const size_t o_C    = 2 * L;
    const size_t o_part = 3 * L;          // conv partials [3L, 8L) (G<=5)
    const size_t o_iq   = 3 * L;
    const size_t o_tq   = 4 * L;
    const size_t o_t1   = 4 * L + T;
    const size_t o_t3   = 4 * L + 2 * T;
    const size_t o_ln2  = 4 * L + 3 * T;
    const size_t o_toh  = 4 * L + 4 * T;
    const size_t o_tnm  = o_toh + 6272;
    const size_t o_st   = o_tnm + 6272;
    const size_t o_wT   = o_st + 1024;
    const size_t o_feat = o_wT + 8 * 38416;
    const size_t o_q    = o_feat + F3;
    const size_t o_fea  = o_q + F3;
    const size_t o_Acm  = o_fea + F3;     // A^T [32,196,196]; gcn dists earlier
    const size_t o_d1   = o_Acm;
    const size_t o_d2   = o_Acm + 524288;
    // conv-phase-only buffers (chunk-major bf16):
    const size_t o_xt1 = 9 * L;                       // 32*5*208*72/2 = 1,198,080 floats
    const size_t o_xt2 = o_xt1 + 1198080;             // 32*2*208*72/2 =   479,232
    const size_t o_wp1 = o_xt2 + 479232;              // 27*128*320/2  =   552,960
    const size_t o_wp2 = o_wp1 + 552960;              // 27*128*128/2  =   221,184
    const size_t o_tr  = o_wp2 + 221184;              // = 9,676,800
    const size_t o_rs  = o_tr + F3;                   // rowsum 32*173

    float* part = W + o_part;
    unsigned short* xt1 = (unsigned short*)(W + o_xt1);
    unsigned short* xt2 = (unsigned short*)(W + o_xt2);
    unsigned short* wp1 = (unsigned short*)(W + o_wp1);
    unsigned short* wp2 = (unsigned short*)(W + o_wp2);
    float* gm1T = W + o_wT + 0 * 38416;
    float* gm2T = W + o_wT + 1 * 38416;
    float* e1T  = W + o_wT + 2 * 38416;
    float* e2T  = W + o_wT + 3 * 38416;
    float* f1T  = W + o_wT + 4 * 38416;
    float* f2T  = W + o_wT + 5 * 38416;
    float* f3T  = W + o_wT + 6 * 38416;
    float* f4T  = W + o_wT + 7 * 38416;

    // ---- conv prep ----
    k_wpack<<<(27 * 128 * 40 + 255) / 256, 256, 0, stream>>>(c1_w1, wp1, 320);
    k_wpack<<<(27 * 128 * 16 + 255) / 256, 256, 0, stream>>>(c1_w2, wp2, 128);
    k_xt_c<<<dim3((5 * 208 * 36 + 255) / 256, 32), 256, 0, stream>>>(x, xt1, 320, 5);

    // ---- conv1: 5 chunks x 2 nh(NT=4) x 2 mh -> 640 blocks ----
    k_convchunk2<320, 5, 4, 2><<<dim3(20, 32), 256, 0, stream>>>(xt1, wp1, part);
    k_reduceG<5><<<3136, 256, 0, stream>>>(part, W + o_A, 802816);
    k_bn_stats<<<128, 256, 0, stream>>>(W + o_A, W + o_st, 128);
    k_bn_apply_relu<<<4096, 256, 0, stream>>>(W + o_A, W + o_st, c1_g1, c1_be1, nullptr, 128);

    // ---- conv2: 2 chunks x 4 nh(NT=2) x 2 mh -> 512 blocks ----
    k_xt_c<<<dim3((2 * 208 * 36 + 255) / 256, 32), 256, 0, stream>>>(W + o_A, xt2, 128, 2);
    k_convchunk2<128, 2, 2, 4><<<dim3(16, 32), 256, 0, stream>>>(xt2, wp2, part);
    k_reduceG<2><<<3136, 256, 0, stream>>>(part, W + o_B, 802816);
    k_bn_stats<<<128, 256, 0, stream>>>(W + o_B, W + o_st + 512, 128);
    k_bn_apply_relu<<<4096, 256, 0, stream>>>(W + o_B, W + o_st + 512, c1_g2, c1_be2,
                                              W + o_tr, 128);

    // ---- weight transposes ----
    P8 p8;
    p8.p[0] = gm1_w; p8.p[1] = gm2_w; p8.p[2] = e1_w; p8.p[3] = e2_w;
    p8.p[4] = f1_w;  p8.p[5] = f2_w;  p8.p[6] = f3_w; p8.p[7] = f4_w;
    k_transpose8<<<dim3(196, 8), 256, 0, stream>>>(p8, W + o_wT);

    // ---- catnum / text ----
    k_catnum<<<196, 64, 0, stream>>>(oneHot, 24, oh_w, oh_b, oh_g, oh_be, W + o_toh);
    k_catnum<<<196, 64, 0, stream>>>(num, 11, nm_w, nm_b, nm_g, nm_be, W + o_tnm);
    k_textbuild<<<32 * 45, 256, 0, stream>>>(W + o_toh, W + o_tnm, W + o_t1, W + o_tr + L);

    // ---- GCN img ----
    k_gcn_dist_t<128, 4><<<dim3(32, 32), 256, 0, stream>>>(W + o_B, W + o_tr, W + o_d1);
    k_gcn_spmmfin_t<128, 4><<<dim3(32, 32), 256, 0, stream>>>(W + o_d1, W + o_B, gm1T,
                                                              gm1_b, W + o_C);
    // ---- GCN text ----
    k_gcn_dist_t<45, 3><<<dim3(15, 32), 256, 0, stream>>>(W + o_t1, W + o_tr + L, W + o_d2);
    k_gcn_spmmfin_t<45, 3><<<dim3(15, 32), 256, 0, stream>>>(W + o_d2, W + o_t1, gm2T,
                                                             gm2_b, W + o_t3);

    // ---- LN + q projections ----
    k_lnlin_t<128, 4><<<dim3(32, 32), 256, 0, stream>>>(W + o_C, ln1_g, ln1_b, e1T, e1_b,
                                                        W + o_B, W + o_iq, W + o_tr);
    k_lnlin_t<45, 3><<<dim3(15, 32), 256, 0, stream>>>(W + o_t3, ln2_g, ln2_b, e2T, e2_b,
                                                       W + o_ln2, W + o_tq, W + o_tr + L);

    // ---- cross-attention -> feat ----
    k_attrow_t<4, 128, 45><<<dim3(32, 32), 256, 0, stream>>>(
        W + o_iq, W + o_tr, W + o_tq, W + o_tr + L,
        f1T, f1_b, f3T, f3_b, W + o_B, W + o_C, W + o_feat, 0);
    k_attrow_t<3, 45, 128><<<dim3(15, 32), 256, 0, stream>>>(
        W + o_tq, W + o_tr + L, W + o_iq, W + o_tr,
        f2T, f2_b, f4T, f4_b, W + o_ln2, W + o_t3, W + o_feat, 128);

    // ---- CMSA ----
    k_conv1x1_t<0, 4><<<dim3(44, 32), 256, 0, stream>>>(W + o_feat, cm_w, cm_b, nullptr,
                                                        W + o_q, W + o_tr);
    k_cmsa_att_t<4><<<dim3(49, 32), 256, 0, stream>>>(W + o_q, W + o_tr, W + o_Acm);
    k_cmsa_apply_t<4><<<dim3(44, 32), 256, 0, stream>>>(W + o_Acm, W + o_q, W + o_fea);
    k_conv1x1_t<1, 4><<<dim3(44, 32), 256, 0, stream>>>(W + o_fea, cmf_w, cmf_b, W + o_feat,
                                                        W + o_q, W + o_rs);

    // ---- final classifier ----
    k_finale<<<32, 256, 0, stream>>>(W + o_toh, W + o_tnm, W + o_rs, cls_w, cls_b, out);
}